// Round 8
// baseline (1369.096 us; speedup 1.0000x reference)
//
#include <hip/hip_runtime.h>

#define HCH 512      // channels
#define LSEQ 4096    // sequence length
#define NB 32        // batch
#define KW 3         // conv kernel width
#define KDIM 1536    // HCH*KW, GEMM K
#define SPAD 1408    // padded chunk slots per sequence (max 1365), 11*128
#define INVS 0.9999950000374997f  // 1/sqrt(1+1e-5)

typedef __attribute__((ext_vector_type(8))) short bf16x8;
typedef __attribute__((ext_vector_type(4))) float f32x4;

__device__ inline unsigned short f2bf(float f) {
  unsigned int u = __float_as_uint(f);
  u += 0x7fffu + ((u >> 16) & 1u);
  return (unsigned short)(u >> 16);
}

__device__ inline void gl_lds16(const void* g, void* l) {
  __builtin_amdgcn_global_load_lds(
      (const __attribute__((address_space(1))) void*)g,
      (__attribute__((address_space(3))) void*)l, 16, 0, 0);
}

// ---- fused prep: zero zeropage+partial, chunk prefix sum, weight transpose
__global__ void prep_all(const float* __restrict__ w1, const float* __restrict__ w2,
                         const float* __restrict__ pw, unsigned short* __restrict__ wt,
                         const int* __restrict__ seq_lens, int* __restrict__ cum,
                         float* __restrict__ pz, int nz) {
  int idx = blockIdx.x * 256 + threadIdx.x;
  if (idx < nz) pz[idx] = 0.f;
  if (idx == 0) {
    int acc = 0;
    for (int b = 0; b < NB; b++) {
      cum[b] = acc;
      acc += (seq_lens[b] - KW) / KW + 1;
    }
  }
  if (idx < 3 * HCH * KDIM) {
    int which = idx / (HCH * KDIM);
    int r = idx % (HCH * KDIM);
    int c = r / KDIM;
    int rem = r % KDIM;
    int k = rem / HCH, ci = rem % HCH;
    const float* src = (which == 0) ? w1 : ((which == 1) ? w2 : pw);
    wt[idx] = f2bf(src[c * KDIM + ci * KW + k]);
  }
}

// ---- layer 0: 1->512 conv + relu + scale/shift, fp32 in, bf16 (b,l,C) out
__global__ void layer0(const float* __restrict__ x, const float* __restrict__ w0,
                       const float* __restrict__ b0, const float* __restrict__ g0,
                       const float* __restrict__ be0, unsigned short* __restrict__ h0) {
  int tid = threadIdx.x;
  int wave = tid >> 6, lane = tid & 63;
  int pos0 = (blockIdx.x * 4 + wave) * 8;      // global flattened (b*4096 + l)
  int l0 = pos0 & (LSEQ - 1);
  int c0 = lane * 8;

  float w[24], bb[8], gg[8], ee[8];
  for (int v = 0; v < 6; v++)
    *reinterpret_cast<float4*>(w + v * 4) = *reinterpret_cast<const float4*>(w0 + c0 * 3 + v * 4);
  for (int v = 0; v < 2; v++) {
    *reinterpret_cast<float4*>(bb + v * 4) = *reinterpret_cast<const float4*>(b0 + c0 + v * 4);
    *reinterpret_cast<float4*>(gg + v * 4) = *reinterpret_cast<const float4*>(g0 + c0 + v * 4);
    *reinterpret_cast<float4*>(ee + v * 4) = *reinterpret_cast<const float4*>(be0 + c0 + v * 4);
  }
  for (int c = 0; c < 8; c++) gg[c] *= INVS;

  const float* xb = x + (size_t)(pos0 - l0);   // batch base
  for (int pp = 0; pp < 8; pp++) {
    int l = l0 + pp;
    float xm1 = (l > 0) ? xb[l - 1] : 0.f;
    float xc = xb[l];
    float xp1 = (l < LSEQ - 1) ? xb[l + 1] : 0.f;
    unsigned int o[4];
    for (int pq = 0; pq < 4; pq++) {
      unsigned int lo = 0, hi = 0;
      for (int s = 0; s < 2; s++) {
        int c = pq * 2 + s;
        float y = w[c * 3] * xm1 + w[c * 3 + 1] * xc + w[c * 3 + 2] * xp1 + bb[c];
        y = fmaxf(y, 0.f);
        unsigned int u = f2bf(gg[c] * y + ee[c]);
        if (s == 0) lo = u; else hi = u;
      }
      o[pq] = lo | (hi << 16);
    }
    uint4 v4; v4.x = o[0]; v4.y = o[1]; v4.z = o[2]; v4.w = o[3];
    *reinterpret_cast<uint4*>(h0 + (size_t)(pos0 + pp) * HCH + c0) = v4;
  }
}

// ---- conv layer as GEMM v8: r4 structure + B double-buffer pipeline ------
// Raw s_barrier + hand s_waitcnt vmcnt(N) keeps B(it+1) DMA in flight across
// the whole compute of iter it (hipBLASLt-style; m135-verified semantics).
__global__ __launch_bounds__(256, 2) void conv_gemm(
    const unsigned short* __restrict__ hin,   // (nb,L,C) bf16
    const unsigned short* __restrict__ wT,    // (512, 1536) bf16 A-layout
    const float* __restrict__ bconv, const float* __restrict__ g,
    const float* __restrict__ be,
    unsigned short* __restrict__ hout,        // (nb,L,C) bf16
    const unsigned short* __restrict__ zp) {
  __shared__ unsigned short As[3 * 128 * 32];    // [k][c 0..127][ci 0..31], 24 KB
  __shared__ unsigned short Bs[2][272 * 32];     // dbuf [row=pos-(l0-1)][ci], 2x17 KB

  int tid = threadIdx.x;
  int wave = tid >> 6, lane = tid & 63;
  int cm = blockIdx.x * 128;                  // out-channel tile
  int ntile = blockIdx.y;
  int b = ntile >> 4;                         // batch-local
  int l0 = (ntile & 15) << 8;                 // 256-position tile
  int wn = wave * 64;                         // wave's position sub-tile
  const size_t hb = (size_t)b * LSEQ * HCH;

  f32x4 acc[8][4] = {};

  int lr = lane >> 2;          // row within a 16-row staging chunk
  int lc = (lane & 3) * 8;     // channel offset (shorts) within 32

  // B staging: wave w stages chunks w*4+t (rows 0..255); wave 3 adds halo 256..257
  const unsigned short* bptr[4];
  for (int t = 0; t < 4; t++) {
    int p = l0 - 1 + (wave * 4 + t) * 16 + lr;
    bptr[t] = (p >= 0 && p < LSEQ) ? (hin + hb + (size_t)p * HCH + lc) : (zp + lc);
  }
  const unsigned short* hptr = zp + lc;
  if (wave == 3 && lane < 8) {
    int p = l0 + 255 + lr;                    // lr in {0,1}
    hptr = (p < LSEQ) ? (hin + hb + (size_t)p * HCH + lc) : (zp + lc);
  }

  // A staging: 24 chunks (3 k-slices x 8 row-groups); wave handles wave*6+t
  const unsigned short* aptr[6];
  unsigned aoff[6];
  for (int t = 0; t < 6; t++) {
    int s = wave * 6 + t;
    int k = s >> 3, c8 = s & 7;
    aptr[t] = wT + (size_t)(cm + c8 * 16 + lr) * KDIM + k * HCH + lc;
    aoff[t] = (unsigned)(k * 4096 + c8 * 512) * 2;   // byte offset in As
  }

  int quad = lane >> 4, mr = lane & 15;

  // prologue: stage A(0) and B(0) into buf 0
  for (int t = 0; t < 6; t++) gl_lds16(aptr[t], (char*)As + aoff[t]);
  for (int t = 0; t < 4; t++)
    gl_lds16(bptr[t], (char*)&Bs[0][0] + (wave * 4 + t) * 1024);
  if (wave == 3) gl_lds16(hptr, (char*)&Bs[0][0] + 256 * 64);

#define STAGE_B(itn, bufn) { int ci0 = (itn) * 32;                                   \
    for (int t = 0; t < 4; t++)                                                      \
      gl_lds16(bptr[t] + ci0, (char*)&Bs[bufn][0] + (wave * 4 + t) * 1024);          \
    if (wave == 3) gl_lds16(hptr + ci0, (char*)&Bs[bufn][0] + 256 * 64); }
#define STAGE_A(itn) { int ci0 = (itn) * 32;                                         \
    for (int t = 0; t < 6; t++) gl_lds16(aptr[t] + ci0, (char*)As + aoff[t]); }
#define WAITB { if (wave == 3) asm volatile("s_waitcnt vmcnt(5)" ::: "memory");      \
                else           asm volatile("s_waitcnt vmcnt(4)" ::: "memory"); }
#define BARRIER asm volatile("s_barrier" ::: "memory");
#define COMPUTE(bufc)                                                                \
  for (int k = 0; k < 3; k++) {                                                      \
    bf16x8 af[8], bfr[4];                                                            \
    for (int i = 0; i < 8; i++)                                                      \
      af[i] = *reinterpret_cast<const bf16x8*>(As + k * 4096 + (i * 16 + mr) * 32 + quad * 8); \
    for (int j = 0; j < 4; j++)                                                      \
      bfr[j] = *reinterpret_cast<const bf16x8*>(&Bs[bufc][0] + (wn + j * 16 + mr + k) * 32 + quad * 8); \
    for (int i = 0; i < 8; i++)                                                      \
      for (int j = 0; j < 4; j++)                                                    \
        acc[i][j] = __builtin_amdgcn_mfma_f32_16x16x32_bf16(af[i], bfr[j], acc[i][j], 0, 0, 0); \
  }

  for (int ith = 0; ith < 8; ith++) {
    int ite = ith * 2;
    STAGE_B(ite + 1, 1);          // B(it+1) stays in flight across compute
    WAITB; BARRIER;               // wait older batches only (B(it), A(it))
    COMPUTE(0);
    BARRIER;                      // all waves done reading buf0/As
    STAGE_A(ite + 1);
    if (ith < 7) {
      STAGE_B(ite + 2, 0);
      WAITB; BARRIER;
      COMPUTE(1);
      BARRIER;
      STAGE_A(ite + 2);
    } else {
      asm volatile("s_waitcnt vmcnt(0)" ::: "memory");
      BARRIER;
      COMPUTE(1);
    }
  }
#undef STAGE_B
#undef STAGE_A
#undef WAITB
#undef BARRIER
#undef COMPUTE

  // epilogue: relu(acc + b) * g*inv + be -> bf16; C/D: col=lane&15,row=quad*4+r
  int nn = lane & 15;
  for (int i = 0; i < 8; i++) {
    int c = cm + i * 16 + quad * 4;
    f32x4 bc = *reinterpret_cast<const f32x4*>(bconv + c);
    f32x4 gg = *reinterpret_cast<const f32x4*>(g + c);
    f32x4 bb = *reinterpret_cast<const f32x4*>(be + c);
    for (int j = 0; j < 4; j++) {
      int n = l0 + wn + j * 16 + nn;
      unsigned long long pack = 0;
      for (int r = 0; r < 4; r++) {
        float y = acc[i][j][r] + bc[r];
        y = fmaxf(y, 0.f);
        unsigned long long u = f2bf(gg[r] * INVS * y + bb[r]);
        pack |= u << (16 * r);
      }
      *reinterpret_cast<unsigned long long*>(hout + hb + (size_t)n * HCH + c) = pack;
    }
  }
}

// ---- chunk einsum GEMM + fused head (r4 version: ci-major, 2 barriers) ---
__global__ __launch_bounds__(256) void chunk_gemm(
    const unsigned short* __restrict__ h2,    // (nb,L,C) bf16
    const unsigned short* __restrict__ wTp,   // (512,1536) bf16 A-layout
    const float* __restrict__ pb, const float* __restrict__ fw,
    const int* __restrict__ seq_q,            // seq_lens for this pass's batches
    const int* __restrict__ cum_q,            // global chunk base per batch
    float* __restrict__ partial,
    const unsigned short* __restrict__ zp) {
  __shared__ unsigned short As[3 * 128 * 32]; // [t][c][ci]
  __shared__ unsigned short Bs[384 * 32];     // [row=p-3*s_base][ci]

  int tid = threadIdx.x;
  int wave = tid >> 6, lane = tid & 63;
  int cm = blockIdx.x * 128;
  int b = blockIdx.y / (SPAD / 128);          // batch-local (uniform per block)
  int s_base = (blockIdx.y % (SPAD / 128)) * 128;
  int p_base = 3 * s_base;
  int slen = seq_q[b];
  int wm = (wave >> 1) * 64;
  int wn = (wave & 1) * 64;
  const size_t hb = (size_t)b * LSEQ * HCH;

  f32x4 acc[4][4] = {};

  int lr = lane >> 2, lc = (lane & 3) * 8;

  const unsigned short* bptr[6];
  const unsigned short* aptr[6];
  unsigned aoff[6];
  for (int t = 0; t < 6; t++) {
    int c = wave * 6 + t;
    int p = p_base + c * 16 + lr;
    bptr[t] = (p < LSEQ) ? (h2 + hb + (size_t)p * HCH + lc) : (zp + lc);
    int k = c >> 3, c8 = c & 7;
    aptr[t] = wTp + (size_t)(cm + c8 * 16 + lr) * KDIM + k * HCH + lc;
    aoff[t] = (unsigned)(k * 4096 + c8 * 512) * 2;
  }

  for (int it = 0; it < 16; it++) {
    int ci0 = it * 32;
    for (int t = 0; t < 6; t++) {
      gl_lds16(aptr[t] + ci0, (char*)As + aoff[t]);
      gl_lds16(bptr[t] + ci0, (char*)Bs + (wave * 6 + t) * 1024);
    }
    __syncthreads();

    int quad = lane >> 4, mr = lane & 15;
    for (int t = 0; t < 3; t++) {
      bf16x8 af[4], bfr[4];
      for (int i = 0; i < 4; i++)
        af[i] = *reinterpret_cast<const bf16x8*>(As + t * 4096 + (wm + i * 16 + mr) * 32 + quad * 8);
      for (int j = 0; j < 4; j++)
        bfr[j] = *reinterpret_cast<const bf16x8*>(Bs + (3 * (wn + j * 16 + mr) + t) * 32 + quad * 8);
      for (int i = 0; i < 4; i++)
        for (int j = 0; j < 4; j++)
          acc[i][j] = __builtin_amdgcn_mfma_f32_16x16x32_bf16(af[i], bfr[j], acc[i][j], 0, 0, 0);
    }
    __syncthreads();
  }

  // fused head: per column s, sum relu(z+pb)*fw over this block's 128 channels
  int quad = lane >> 4, nn = lane & 15;
  for (int j = 0; j < 4; j++) {
    float s = 0.f;
    for (int i = 0; i < 4; i++) {
      int c = cm + wm + i * 16 + quad * 4;
      f32x4 pbv = *reinterpret_cast<const f32x4*>(pb + c);
      f32x4 fwv = *reinterpret_cast<const f32x4*>(fw + c);
      for (int r = 0; r < 4; r++) {
        float z = acc[i][j][r] + pbv[r];
        z = fmaxf(z, 0.f);
        s += z * fwv[r];
      }
    }
    s += __shfl_xor(s, 16, 64);
    s += __shfl_xor(s, 32, 64);
    if (quad == 0) {
      int sc = s_base + wn + j * 16 + nn;
      if (3 * sc + KW <= slen) atomicAdd(partial + cum_q[b] + sc, s);
    }
  }
}

// ---- final: sigmoid(partial + fb) ----------------------------------------
__global__ void finalize(const float* __restrict__ partial, const float* __restrict__ fb,
                         float* __restrict__ out, int n) {
  int i = blockIdx.x * 256 + threadIdx.x;
  if (i < n) {
    float t = partial[i] + fb[0];
    out[i] = 1.f / (1.f + expf(-t));
  }
}

extern "C" void kernel_launch(void* const* d_in, const int* in_sizes, int n_in,
                              void* d_out, int out_size, void* d_ws, size_t ws_size,
                              hipStream_t stream) {
  (void)in_sizes; (void)n_in;
  const float* x   = (const float*)d_in[0];
  const float* w0  = (const float*)d_in[1];
  const float* b0  = (const float*)d_in[2];
  const float* g0  = (const float*)d_in[3];
  const float* be0 = (const float*)d_in[4];
  const float* w1  = (const float*)d_in[5];
  const float* b1  = (const float*)d_in[6];
  const float* g1  = (const float*)d_in[7];
  const float* be1 = (const float*)d_in[8];
  const float* w2  = (const float*)d_in[9];
  const float* b2  = (const float*)d_in[10];
  const float* g2  = (const float*)d_in[11];
  const float* be2 = (const float*)d_in[12];
  const float* pw  = (const float*)d_in[13];
  const float* pb  = (const float*)d_in[14];
  const float* fw  = (const float*)d_in[15];
  const float* fb  = (const float*)d_in[16];
  const int* seq_lens = (const int*)d_in[17];

  char* ws = (char*)d_ws;
  unsigned short* zeropage = (unsigned short*)ws;          // 4096 B, zeroed
  float* partial = (float*)(ws + 4096);                    // out_size floats, zeroed
  size_t off = 4096 + (size_t)out_size * 4;
  off = (off + 255) & ~(size_t)255;
  int* cum = (int*)(ws + off);                             // NB ints
  off += NB * 4;
  off = (off + 255) & ~(size_t)255;
  unsigned short* wt = (unsigned short*)(ws + off);        // 3 x 512 x 1536 bf16
  off += (size_t)3 * HCH * KDIM * 2;
  off = (off + 255) & ~(size_t)255;
  size_t fixed = off;

  // pick largest power-of-two batches-per-pass whose 2 ping-pong buffers fit
  const size_t per_batch = (size_t)LSEQ * HCH * 2;         // 4 MiB
  int nb_pass = NB;
  while (nb_pass > 1 && fixed + 2 * per_batch * (size_t)nb_pass > ws_size)
    nb_pass >>= 1;
  unsigned short* h0 = (unsigned short*)(ws + fixed);
  unsigned short* h1 = h0 + (size_t)nb_pass * LSEQ * HCH;

  int nzero = 1024 + out_size;   // zeropage (1024 floats) + partial
  prep_all<<<(3 * HCH * KDIM) / 256, 256, 0, stream>>>(w1, w2, pw, wt, seq_lens, cum,
                                                       (float*)ws, nzero);

  int npass = NB / nb_pass;
  for (int q = 0; q < npass; q++) {
    const float* xq = x + (size_t)q * nb_pass * LSEQ;
    layer0<<<nb_pass * (LSEQ / 32), 256, 0, stream>>>(xq, w0, b0, g0, be0, h0);
    conv_gemm<<<dim3(4, nb_pass * 16), 256, 0, stream>>>(h0, wt, b1, g1, be1, h1, zeropage);
    conv_gemm<<<dim3(4, nb_pass * 16), 256, 0, stream>>>(h1, wt + (size_t)HCH * KDIM,
                                                         b2, g2, be2, h0, zeropage);
    chunk_gemm<<<dim3(4, nb_pass * (SPAD / 128)), 256, 0, stream>>>(
        h0, wt + (size_t)2 * HCH * KDIM, pb, fw,
        seq_lens + q * nb_pass, cum + q * nb_pass, partial, zeropage);
  }
  finalize<<<(out_size + 255) / 256, 256, 0, stream>>>(partial, fb, (float*)d_out, out_size);
}

// Round 9
// 667.997 us; speedup vs baseline: 2.0496x; 2.0496x over previous
//
#include <hip/hip_runtime.h>

#define HCH 512      // channels
#define LSEQ 4096    // sequence length
#define NB 32        // batch
#define KW 3         // conv kernel width
#define KDIM 1536    // HCH*KW, GEMM K
#define SPAD 1408    // padded chunk slots per sequence (max 1365), 11*128
#define INVS 0.9999950000374997f  // 1/sqrt(1+1e-5)

typedef __attribute__((ext_vector_type(8))) short bf16x8;
typedef __attribute__((ext_vector_type(4))) float f32x4;

__device__ inline unsigned short f2bf(float f) {
  unsigned int u = __float_as_uint(f);
  u += 0x7fffu + ((u >> 16) & 1u);
  return (unsigned short)(u >> 16);
}

__device__ inline void gl_lds16(const void* g, void* l) {
  __builtin_amdgcn_global_load_lds(
      (const __attribute__((address_space(1))) void*)g,
      (__attribute__((address_space(3))) void*)l, 16, 0, 0);
}

// ---- fused prep: zero zeropage+partial, chunk prefix sum, weight transpose
__global__ void prep_all(const float* __restrict__ w1, const float* __restrict__ w2,
                         const float* __restrict__ pw, unsigned short* __restrict__ wt,
                         const int* __restrict__ seq_lens, int* __restrict__ cum,
                         float* __restrict__ pz, int nz) {
  int idx = blockIdx.x * 256 + threadIdx.x;
  if (idx < nz) pz[idx] = 0.f;
  if (idx == 0) {
    int acc = 0;
    for (int b = 0; b < NB; b++) {
      cum[b] = acc;
      acc += (seq_lens[b] - KW) / KW + 1;
    }
  }
  if (idx < 3 * HCH * KDIM) {
    int which = idx / (HCH * KDIM);
    int r = idx % (HCH * KDIM);
    int c = r / KDIM;
    int rem = r % KDIM;
    int k = rem / HCH, ci = rem % HCH;
    const float* src = (which == 0) ? w1 : ((which == 1) ? w2 : pw);
    wt[idx] = f2bf(src[c * KDIM + ci * KW + k]);
  }
}

// ---- layer 0: 1->512 conv + relu + scale/shift, fp32 in, bf16 (b,l,C) out
__global__ void layer0(const float* __restrict__ x, const float* __restrict__ w0,
                       const float* __restrict__ b0, const float* __restrict__ g0,
                       const float* __restrict__ be0, unsigned short* __restrict__ h0) {
  int tid = threadIdx.x;
  int wave = tid >> 6, lane = tid & 63;
  int pos0 = (blockIdx.x * 4 + wave) * 8;      // global flattened (b*4096 + l)
  int l0 = pos0 & (LSEQ - 1);
  int c0 = lane * 8;

  float w[24], bb[8], gg[8], ee[8];
  for (int v = 0; v < 6; v++)
    *reinterpret_cast<float4*>(w + v * 4) = *reinterpret_cast<const float4*>(w0 + c0 * 3 + v * 4);
  for (int v = 0; v < 2; v++) {
    *reinterpret_cast<float4*>(bb + v * 4) = *reinterpret_cast<const float4*>(b0 + c0 + v * 4);
    *reinterpret_cast<float4*>(gg + v * 4) = *reinterpret_cast<const float4*>(g0 + c0 + v * 4);
    *reinterpret_cast<float4*>(ee + v * 4) = *reinterpret_cast<const float4*>(be0 + c0 + v * 4);
  }
  for (int c = 0; c < 8; c++) gg[c] *= INVS;

  const float* xb = x + (size_t)(pos0 - l0);   // batch base
  for (int pp = 0; pp < 8; pp++) {
    int l = l0 + pp;
    float xm1 = (l > 0) ? xb[l - 1] : 0.f;
    float xc = xb[l];
    float xp1 = (l < LSEQ - 1) ? xb[l + 1] : 0.f;
    unsigned int o[4];
    for (int pq = 0; pq < 4; pq++) {
      unsigned int lo = 0, hi = 0;
      for (int s = 0; s < 2; s++) {
        int c = pq * 2 + s;
        float y = w[c * 3] * xm1 + w[c * 3 + 1] * xc + w[c * 3 + 2] * xp1 + bb[c];
        y = fmaxf(y, 0.f);
        unsigned int u = f2bf(gg[c] * y + ee[c]);
        if (s == 0) lo = u; else hi = u;
      }
      o[pq] = lo | (hi << 16);
    }
    uint4 v4; v4.x = o[0]; v4.y = o[1]; v4.z = o[2]; v4.w = o[3];
    *reinterpret_cast<uint4*>(h0 + (size_t)(pos0 + pp) * HCH + c0) = v4;
  }
}

// ---- conv layer as GEMM (r4-best): block 128x256, wave 128x64 (8x4 acc) --
// 16 ci-iters x 3 k-slices; B staged once per position; 96 MFMA/iter/wave.
// NOTE (r7/r8 lessons): A-frags MUST come from LDS (global A = latency-bound
// 2x regression); hand vmcnt/s_barrier pipelining spills acc (2.5x regression).
__global__ __launch_bounds__(256, 2) void conv_gemm(
    const unsigned short* __restrict__ hin,   // (nb,L,C) bf16
    const unsigned short* __restrict__ wT,    // (512, 1536) bf16 A-layout
    const float* __restrict__ bconv, const float* __restrict__ g,
    const float* __restrict__ be,
    unsigned short* __restrict__ hout,        // (nb,L,C) bf16
    const unsigned short* __restrict__ zp) {
  __shared__ unsigned short As[3 * 128 * 32];  // [k][c 0..127][ci 0..31]
  __shared__ unsigned short Bs[272 * 32];      // [row=pos-(l0-1)][ci]; 258 used

  int tid = threadIdx.x;
  int wave = tid >> 6, lane = tid & 63;
  int cm = blockIdx.x * 128;                  // out-channel tile
  int ntile = blockIdx.y;
  int b = ntile >> 4;                         // batch-local
  int l0 = (ntile & 15) << 8;                 // 256-position tile
  int wn = wave * 64;                         // wave's position sub-tile
  const size_t hb = (size_t)b * LSEQ * HCH;

  f32x4 acc[8][4] = {};

  int lr = lane >> 2;          // row within a 16-row staging chunk
  int lc = (lane & 3) * 8;     // channel offset (shorts) within 32

  // B staging: wave w stages chunks w*4+t (rows 0..255); wave 3 adds halo 256..257
  const unsigned short* bptr[4];
  for (int t = 0; t < 4; t++) {
    int p = l0 - 1 + (wave * 4 + t) * 16 + lr;
    bptr[t] = (p >= 0 && p < LSEQ) ? (hin + hb + (size_t)p * HCH + lc) : (zp + lc);
  }
  const unsigned short* hptr = zp + lc;
  if (wave == 3 && lane < 8) {
    int p = l0 + 255 + lr;                    // lr in {0,1}
    hptr = (p < LSEQ) ? (hin + hb + (size_t)p * HCH + lc) : (zp + lc);
  }

  // A staging: 24 chunks (3 k-slices x 8 row-groups); wave handles wave*6+t
  const unsigned short* aptr[6];
  unsigned aoff[6];
  for (int t = 0; t < 6; t++) {
    int s = wave * 6 + t;
    int k = s >> 3, c8 = s & 7;
    aptr[t] = wT + (size_t)(cm + c8 * 16 + lr) * KDIM + k * HCH + lc;
    aoff[t] = (unsigned)(k * 4096 + c8 * 512) * 2;   // byte offset in As
  }

  for (int it = 0; it < 16; it++) {
    int ci0 = it * 32;
    for (int t = 0; t < 6; t++)
      gl_lds16(aptr[t] + ci0, (char*)As + aoff[t]);
    for (int t = 0; t < 4; t++)
      gl_lds16(bptr[t] + ci0, (char*)Bs + (wave * 4 + t) * 1024);
    if (wave == 3)
      gl_lds16(hptr + ci0, (char*)Bs + 256 * 64);  // lanes>=8 land in scratch
    __syncthreads();

    int quad = lane >> 4, mr = lane & 15;
    for (int k = 0; k < 3; k++) {
      bf16x8 af[8], bfr[4];
      for (int i = 0; i < 8; i++)
        af[i] = *reinterpret_cast<const bf16x8*>(As + k * 4096 + (i * 16 + mr) * 32 + quad * 8);
      for (int j = 0; j < 4; j++)
        bfr[j] = *reinterpret_cast<const bf16x8*>(Bs + (wn + j * 16 + mr + k) * 32 + quad * 8);
      for (int i = 0; i < 8; i++)
        for (int j = 0; j < 4; j++)
          acc[i][j] = __builtin_amdgcn_mfma_f32_16x16x32_bf16(af[i], bfr[j], acc[i][j], 0, 0, 0);
    }
    __syncthreads();
  }

  // epilogue: relu(acc + b) * g*inv + be -> bf16; C/D: col=lane&15,row=quad*4+r
  int quad = lane >> 4, nn = lane & 15;
  for (int i = 0; i < 8; i++) {
    int c = cm + i * 16 + quad * 4;
    f32x4 bc = *reinterpret_cast<const f32x4*>(bconv + c);
    f32x4 gg = *reinterpret_cast<const f32x4*>(g + c);
    f32x4 bb = *reinterpret_cast<const f32x4*>(be + c);
    for (int j = 0; j < 4; j++) {
      int n = l0 + wn + j * 16 + nn;
      unsigned long long pack = 0;
      for (int r = 0; r < 4; r++) {
        float y = acc[i][j][r] + bc[r];
        y = fmaxf(y, 0.f);
        unsigned long long u = f2bf(gg[r] * INVS * y + bb[r]);
        pack |= u << (16 * r);
      }
      *reinterpret_cast<unsigned long long*>(hout + hb + (size_t)n * HCH + c) = pack;
    }
  }
}

// ---- chunk einsum GEMM + fused head (r4 + whole-block early exit) --------
__global__ __launch_bounds__(256) void chunk_gemm(
    const unsigned short* __restrict__ h2,    // (nb,L,C) bf16
    const unsigned short* __restrict__ wTp,   // (512,1536) bf16 A-layout
    const float* __restrict__ pb, const float* __restrict__ fw,
    const int* __restrict__ seq_q,            // seq_lens for this pass's batches
    const int* __restrict__ cum_q,            // global chunk base per batch
    float* __restrict__ partial,
    const unsigned short* __restrict__ zp) {
  __shared__ unsigned short As[3 * 128 * 32]; // [t][c][ci]
  __shared__ unsigned short Bs[384 * 32];     // [row=p-3*s_base][ci]

  int tid = threadIdx.x;
  int wave = tid >> 6, lane = tid & 63;
  int cm = blockIdx.x * 128;
  int b = blockIdx.y / (SPAD / 128);          // batch-local (uniform per block)
  int s_base = (blockIdx.y % (SPAD / 128)) * 128;
  int slen = seq_q[b];
  // whole block past this sequence's chunk range: nothing to contribute
  if (3 * s_base + KW > slen) return;
  int p_base = 3 * s_base;
  int wm = (wave >> 1) * 64;
  int wn = (wave & 1) * 64;
  const size_t hb = (size_t)b * LSEQ * HCH;

  f32x4 acc[4][4] = {};

  int lr = lane >> 2, lc = (lane & 3) * 8;

  const unsigned short* bptr[6];
  const unsigned short* aptr[6];
  unsigned aoff[6];
  for (int t = 0; t < 6; t++) {
    int c = wave * 6 + t;
    int p = p_base + c * 16 + lr;
    bptr[t] = (p < LSEQ) ? (h2 + hb + (size_t)p * HCH + lc) : (zp + lc);
    int k = c >> 3, c8 = c & 7;
    aptr[t] = wTp + (size_t)(cm + c8 * 16 + lr) * KDIM + k * HCH + lc;
    aoff[t] = (unsigned)(k * 4096 + c8 * 512) * 2;
  }

  for (int it = 0; it < 16; it++) {
    int ci0 = it * 32;
    for (int t = 0; t < 6; t++) {
      gl_lds16(aptr[t] + ci0, (char*)As + aoff[t]);
      gl_lds16(bptr[t] + ci0, (char*)Bs + (wave * 6 + t) * 1024);
    }
    __syncthreads();

    int quad = lane >> 4, mr = lane & 15;
    for (int t = 0; t < 3; t++) {
      bf16x8 af[4], bfr[4];
      for (int i = 0; i < 4; i++)
        af[i] = *reinterpret_cast<const bf16x8*>(As + t * 4096 + (wm + i * 16 + mr) * 32 + quad * 8);
      for (int j = 0; j < 4; j++)
        bfr[j] = *reinterpret_cast<const bf16x8*>(Bs + (3 * (wn + j * 16 + mr) + t) * 32 + quad * 8);
      for (int i = 0; i < 4; i++)
        for (int j = 0; j < 4; j++)
          acc[i][j] = __builtin_amdgcn_mfma_f32_16x16x32_bf16(af[i], bfr[j], acc[i][j], 0, 0, 0);
    }
    __syncthreads();
  }

  // fused head: per column s, sum relu(z+pb)*fw over this block's 128 channels
  int quad = lane >> 4, nn = lane & 15;
  for (int j = 0; j < 4; j++) {
    float s = 0.f;
    for (int i = 0; i < 4; i++) {
      int c = cm + wm + i * 16 + quad * 4;
      f32x4 pbv = *reinterpret_cast<const f32x4*>(pb + c);
      f32x4 fwv = *reinterpret_cast<const f32x4*>(fw + c);
      for (int r = 0; r < 4; r++) {
        float z = acc[i][j][r] + pbv[r];
        z = fmaxf(z, 0.f);
        s += z * fwv[r];
      }
    }
    s += __shfl_xor(s, 16, 64);
    s += __shfl_xor(s, 32, 64);
    if (quad == 0) {
      int sc = s_base + wn + j * 16 + nn;
      if (3 * sc + KW <= slen) atomicAdd(partial + cum_q[b] + sc, s);
    }
  }
}

// ---- final: sigmoid(partial + fb) ----------------------------------------
__global__ void finalize(const float* __restrict__ partial, const float* __restrict__ fb,
                         float* __restrict__ out, int n) {
  int i = blockIdx.x * 256 + threadIdx.x;
  if (i < n) {
    float t = partial[i] + fb[0];
    out[i] = 1.f / (1.f + expf(-t));
  }
}

extern "C" void kernel_launch(void* const* d_in, const int* in_sizes, int n_in,
                              void* d_out, int out_size, void* d_ws, size_t ws_size,
                              hipStream_t stream) {
  (void)in_sizes; (void)n_in;
  const float* x   = (const float*)d_in[0];
  const float* w0  = (const float*)d_in[1];
  const float* b0  = (const float*)d_in[2];
  const float* g0  = (const float*)d_in[3];
  const float* be0 = (const float*)d_in[4];
  const float* w1  = (const float*)d_in[5];
  const float* b1  = (const float*)d_in[6];
  const float* g1  = (const float*)d_in[7];
  const float* be1 = (const float*)d_in[8];
  const float* w2  = (const float*)d_in[9];
  const float* b2  = (const float*)d_in[10];
  const float* g2  = (const float*)d_in[11];
  const float* be2 = (const float*)d_in[12];
  const float* pw  = (const float*)d_in[13];
  const float* pb  = (const float*)d_in[14];
  const float* fw  = (const float*)d_in[15];
  const float* fb  = (const float*)d_in[16];
  const int* seq_lens = (const int*)d_in[17];

  char* ws = (char*)d_ws;
  unsigned short* zeropage = (unsigned short*)ws;          // 4096 B, zeroed
  float* partial = (float*)(ws + 4096);                    // out_size floats, zeroed
  size_t off = 4096 + (size_t)out_size * 4;
  off = (off + 255) & ~(size_t)255;
  int* cum = (int*)(ws + off);                             // NB ints
  off += NB * 4;
  off = (off + 255) & ~(size_t)255;
  unsigned short* wt = (unsigned short*)(ws + off);        // 3 x 512 x 1536 bf16
  off += (size_t)3 * HCH * KDIM * 2;
  off = (off + 255) & ~(size_t)255;
  size_t fixed = off;

  // pick largest power-of-two batches-per-pass whose 2 ping-pong buffers fit
  const size_t per_batch = (size_t)LSEQ * HCH * 2;         // 4 MiB
  int nb_pass = NB;
  while (nb_pass > 1 && fixed + 2 * per_batch * (size_t)nb_pass > ws_size)
    nb_pass >>= 1;
  unsigned short* h0 = (unsigned short*)(ws + fixed);
  unsigned short* h1 = h0 + (size_t)nb_pass * LSEQ * HCH;

  int nzero = 1024 + out_size;   // zeropage (1024 floats) + partial
  prep_all<<<(3 * HCH * KDIM) / 256, 256, 0, stream>>>(w1, w2, pw, wt, seq_lens, cum,
                                                       (float*)ws, nzero);

  int npass = NB / nb_pass;
  for (int q = 0; q < npass; q++) {
    const float* xq = x + (size_t)q * nb_pass * LSEQ;
    layer0<<<nb_pass * (LSEQ / 32), 256, 0, stream>>>(xq, w0, b0, g0, be0, h0);
    conv_gemm<<<dim3(4, nb_pass * 16), 256, 0, stream>>>(h0, wt, b1, g1, be1, h1, zeropage);
    conv_gemm<<<dim3(4, nb_pass * 16), 256, 0, stream>>>(h1, wt + (size_t)HCH * KDIM,
                                                         b2, g2, be2, h0, zeropage);
    chunk_gemm<<<dim3(4, nb_pass * (SPAD / 128)), 256, 0, stream>>>(
        h0, wt + (size_t)2 * HCH * KDIM, pb, fw,
        seq_lens + q * nb_pass, cum + q * nb_pass, partial, zeropage);
  }
  finalize<<<(out_size + 255) / 256, 256, 0, stream>>>(partial, fb, (float*)d_out, out_size);
}

// Round 11
// 642.753 us; speedup vs baseline: 2.1301x; 1.0393x over previous
//
#include <hip/hip_runtime.h>

#define HCH 512      // channels
#define LSEQ 4096    // sequence length
#define NB 32        // batch
#define KW 3         // conv kernel width
#define KDIM 1536    // HCH*KW, GEMM K
#define SPAD 1408    // padded chunk slots per sequence (max 1365), 11*128
#define INVS 0.9999950000374997f  // 1/sqrt(1+1e-5)

typedef __attribute__((ext_vector_type(8))) short bf16x8;
typedef __attribute__((ext_vector_type(4))) float f32x4;

__device__ inline unsigned short f2bf(float f) {
  unsigned int u = __float_as_uint(f);
  u += 0x7fffu + ((u >> 16) & 1u);
  return (unsigned short)(u >> 16);
}

__device__ inline void gl_lds16(const void* g, void* l) {
  __builtin_amdgcn_global_load_lds(
      (const __attribute__((address_space(1))) void*)g,
      (__attribute__((address_space(3))) void*)l, 16, 0, 0);
}

// ---- fused prep: zero zeropage+partial, chunk prefix sum, weight transpose
__global__ void prep_all(const float* __restrict__ w1, const float* __restrict__ w2,
                         const float* __restrict__ pw, unsigned short* __restrict__ wt,
                         const int* __restrict__ seq_lens, int* __restrict__ cum,
                         float* __restrict__ pz, int nz) {
  int idx = blockIdx.x * 256 + threadIdx.x;
  if (idx < nz) pz[idx] = 0.f;
  if (idx == 0) {
    int acc = 0;
    for (int b = 0; b < NB; b++) {
      cum[b] = acc;
      acc += (seq_lens[b] - KW) / KW + 1;
    }
  }
  if (idx < 3 * HCH * KDIM) {
    int which = idx / (HCH * KDIM);
    int r = idx % (HCH * KDIM);
    int c = r / KDIM;
    int rem = r % KDIM;
    int k = rem / HCH, ci = rem % HCH;
    const float* src = (which == 0) ? w1 : ((which == 1) ? w2 : pw);
    wt[idx] = f2bf(src[c * KDIM + ci * KW + k]);
  }
}

// ---- layer 0: 1->512 conv + relu + scale/shift, fp32 in, bf16 (b,l,C) out
// waves past seq_len+1 produce dead data -> early exit (consumers skip too)
__global__ void layer0(const float* __restrict__ x, const float* __restrict__ w0,
                       const float* __restrict__ b0, const float* __restrict__ g0,
                       const float* __restrict__ be0, unsigned short* __restrict__ h0,
                       const int* __restrict__ seq_q) {
  int tid = threadIdx.x;
  int wave = tid >> 6, lane = tid & 63;
  int pos0 = (blockIdx.x * 4 + wave) * 8;      // flattened (b_local*4096 + l)
  int l0 = pos0 & (LSEQ - 1);
  if (l0 >= seq_q[pos0 >> 12] + 2) return;     // h0 needed only for l <= slen+1
  int c0 = lane * 8;

  float w[24], bb[8], gg[8], ee[8];
  for (int v = 0; v < 6; v++)
    *reinterpret_cast<float4*>(w + v * 4) = *reinterpret_cast<const float4*>(w0 + c0 * 3 + v * 4);
  for (int v = 0; v < 2; v++) {
    *reinterpret_cast<float4*>(bb + v * 4) = *reinterpret_cast<const float4*>(b0 + c0 + v * 4);
    *reinterpret_cast<float4*>(gg + v * 4) = *reinterpret_cast<const float4*>(g0 + c0 + v * 4);
    *reinterpret_cast<float4*>(ee + v * 4) = *reinterpret_cast<const float4*>(be0 + c0 + v * 4);
  }
  for (int c = 0; c < 8; c++) gg[c] *= INVS;

  const float* xb = x + (size_t)(pos0 - l0);   // batch base
  for (int pp = 0; pp < 8; pp++) {
    int l = l0 + pp;
    float xm1 = (l > 0) ? xb[l - 1] : 0.f;
    float xc = xb[l];
    float xp1 = (l < LSEQ - 1) ? xb[l + 1] : 0.f;
    unsigned int o[4];
    for (int pq = 0; pq < 4; pq++) {
      unsigned int lo = 0, hi = 0;
      for (int s = 0; s < 2; s++) {
        int c = pq * 2 + s;
        float y = w[c * 3] * xm1 + w[c * 3 + 1] * xc + w[c * 3 + 2] * xp1 + bb[c];
        y = fmaxf(y, 0.f);
        unsigned int u = f2bf(gg[c] * y + ee[c]);
        if (s == 0) lo = u; else hi = u;
      }
      o[pq] = lo | (hi << 16);
    }
    uint4 v4; v4.x = o[0]; v4.y = o[1]; v4.z = o[2]; v4.w = o[3];
    *reinterpret_cast<uint4*>(h0 + (size_t)(pos0 + pp) * HCH + c0) = v4;
  }
}

// ---- conv layer as GEMM (r4-best + seq-length early exit) ----------------
// block 128x256, wave 128x64 (8x4 acc); 16 ci-iters x 3 k-slices.
// Tiles fully past seq_len+margin are dead (consumers guard reads) -> skip.
// NOTE (r7/r8): A-frags MUST come from LDS; no hand vmcnt pipelining.
__global__ __launch_bounds__(256, 2) void conv_gemm(
    const unsigned short* __restrict__ hin,   // (nb,L,C) bf16
    const unsigned short* __restrict__ wT,    // (512, 1536) bf16 A-layout
    const float* __restrict__ bconv, const float* __restrict__ g,
    const float* __restrict__ be,
    unsigned short* __restrict__ hout,        // (nb,L,C) bf16
    const unsigned short* __restrict__ zp,
    const int* __restrict__ seq_q, int margin) {
  __shared__ unsigned short As[3 * 128 * 32];  // [k][c 0..127][ci 0..31]
  __shared__ unsigned short Bs[272 * 32];      // [row=pos-(l0-1)][ci]; 258 used

  int tid = threadIdx.x;
  int wave = tid >> 6, lane = tid & 63;
  int cm = blockIdx.x * 128;                  // out-channel tile
  int ntile = blockIdx.y;
  int b = ntile >> 4;                         // batch-local
  int l0 = (ntile & 15) << 8;                 // 256-position tile
  int limit = seq_q[b] + margin;              // outputs needed for n < limit
  if (l0 >= limit) return;                    // block-uniform, pre-barrier
  int wn = wave * 64;                         // wave's position sub-tile
  const size_t hb = (size_t)b * LSEQ * HCH;

  f32x4 acc[8][4] = {};

  int lr = lane >> 2;          // row within a 16-row staging chunk
  int lc = (lane & 3) * 8;     // channel offset (shorts) within 32

  // B staging: wave w stages chunks w*4+t (rows 0..255); wave 3 adds halo 256..257
  const unsigned short* bptr[4];
  for (int t = 0; t < 4; t++) {
    int p = l0 - 1 + (wave * 4 + t) * 16 + lr;
    bptr[t] = (p >= 0 && p < LSEQ) ? (hin + hb + (size_t)p * HCH + lc) : (zp + lc);
  }
  const unsigned short* hptr = zp + lc;
  if (wave == 3 && lane < 8) {
    int p = l0 + 255 + lr;                    // lr in {0,1}
    hptr = (p < LSEQ) ? (hin + hb + (size_t)p * HCH + lc) : (zp + lc);
  }

  // A staging: 24 chunks (3 k-slices x 8 row-groups); wave handles wave*6+t
  const unsigned short* aptr[6];
  unsigned aoff[6];
  for (int t = 0; t < 6; t++) {
    int s = wave * 6 + t;
    int k = s >> 3, c8 = s & 7;
    aptr[t] = wT + (size_t)(cm + c8 * 16 + lr) * KDIM + k * HCH + lc;
    aoff[t] = (unsigned)(k * 4096 + c8 * 512) * 2;   // byte offset in As
  }

  for (int it = 0; it < 16; it++) {
    int ci0 = it * 32;
    for (int t = 0; t < 6; t++)
      gl_lds16(aptr[t] + ci0, (char*)As + aoff[t]);
    for (int t = 0; t < 4; t++)
      gl_lds16(bptr[t] + ci0, (char*)Bs + (wave * 4 + t) * 1024);
    if (wave == 3)
      gl_lds16(hptr + ci0, (char*)Bs + 256 * 64);  // lanes>=8 land in scratch
    __syncthreads();

    int quad = lane >> 4, mr = lane & 15;
    for (int k = 0; k < 3; k++) {
      bf16x8 af[8], bfr[4];
      for (int i = 0; i < 8; i++)
        af[i] = *reinterpret_cast<const bf16x8*>(As + k * 4096 + (i * 16 + mr) * 32 + quad * 8);
      for (int j = 0; j < 4; j++)
        bfr[j] = *reinterpret_cast<const bf16x8*>(Bs + (wn + j * 16 + mr + k) * 32 + quad * 8);
      for (int i = 0; i < 8; i++)
        for (int j = 0; j < 4; j++)
          acc[i][j] = __builtin_amdgcn_mfma_f32_16x16x32_bf16(af[i], bfr[j], acc[i][j], 0, 0, 0);
    }
    __syncthreads();
  }

  // epilogue: relu(acc + b) * g*inv + be -> bf16; C/D: col=lane&15,row=quad*4+r
  // dead positions (n >= limit) not stored — consumers never read them.
  int quad = lane >> 4, nn = lane & 15;
  for (int i = 0; i < 8; i++) {
    int c = cm + i * 16 + quad * 4;
    f32x4 bc = *reinterpret_cast<const f32x4*>(bconv + c);
    f32x4 gg = *reinterpret_cast<const f32x4*>(g + c);
    f32x4 bb = *reinterpret_cast<const f32x4*>(be + c);
    for (int j = 0; j < 4; j++) {
      int n = l0 + wn + j * 16 + nn;
      if (n >= limit) continue;
      unsigned long long pack = 0;
      for (int r = 0; r < 4; r++) {
        float y = acc[i][j][r] + bc[r];
        y = fmaxf(y, 0.f);
        unsigned long long u = f2bf(gg[r] * INVS * y + bb[r]);
        pack |= u << (16 * r);
      }
      *reinterpret_cast<unsigned long long*>(hout + hb + (size_t)n * HCH + c) = pack;
    }
  }
}

// ---- chunk einsum GEMM + fused head (r4 + whole-block early exit) --------
__global__ __launch_bounds__(256) void chunk_gemm(
    const unsigned short* __restrict__ h2,    // (nb,L,C) bf16
    const unsigned short* __restrict__ wTp,   // (512,1536) bf16 A-layout
    const float* __restrict__ pb, const float* __restrict__ fw,
    const int* __restrict__ seq_q,            // seq_lens for this pass's batches
    const int* __restrict__ cum_q,            // global chunk base per batch
    float* __restrict__ partial,
    const unsigned short* __restrict__ zp) {
  __shared__ unsigned short As[3 * 128 * 32]; // [t][c][ci]
  __shared__ unsigned short Bs[384 * 32];     // [row=p-3*s_base][ci]

  int tid = threadIdx.x;
  int wave = tid >> 6, lane = tid & 63;
  int cm = blockIdx.x * 128;
  int b = blockIdx.y / (SPAD / 128);          // batch-local (uniform per block)
  int s_base = (blockIdx.y % (SPAD / 128)) * 128;
  int slen = seq_q[b];
  // whole block past this sequence's chunk range: nothing to contribute
  if (3 * s_base + KW > slen) return;
  int p_base = 3 * s_base;
  int wm = (wave >> 1) * 64;
  int wn = (wave & 1) * 64;
  const size_t hb = (size_t)b * LSEQ * HCH;

  f32x4 acc[4][4] = {};

  int lr = lane >> 2, lc = (lane & 3) * 8;

  const unsigned short* bptr[6];
  const unsigned short* aptr[6];
  unsigned aoff[6];
  for (int t = 0; t < 6; t++) {
    int c = wave * 6 + t;
    int p = p_base + c * 16 + lr;
    bptr[t] = (p < LSEQ) ? (h2 + hb + (size_t)p * HCH + lc) : (zp + lc);
    int k = c >> 3, c8 = c & 7;
    aptr[t] = wTp + (size_t)(cm + c8 * 16 + lr) * KDIM + k * HCH + lc;
    aoff[t] = (unsigned)(k * 4096 + c8 * 512) * 2;
  }

  for (int it = 0; it < 16; it++) {
    int ci0 = it * 32;
    for (int t = 0; t < 6; t++) {
      gl_lds16(aptr[t] + ci0, (char*)As + aoff[t]);
      gl_lds16(bptr[t] + ci0, (char*)Bs + (wave * 6 + t) * 1024);
    }
    __syncthreads();

    int quad = lane >> 4, mr = lane & 15;
    for (int t = 0; t < 3; t++) {
      bf16x8 af[4], bfr[4];
      for (int i = 0; i < 4; i++)
        af[i] = *reinterpret_cast<const bf16x8*>(As + t * 4096 + (wm + i * 16 + mr) * 32 + quad * 8);
      for (int j = 0; j < 4; j++)
        bfr[j] = *reinterpret_cast<const bf16x8*>(Bs + (3 * (wn + j * 16 + mr) + t) * 32 + quad * 8);
      for (int i = 0; i < 4; i++)
        for (int j = 0; j < 4; j++)
          acc[i][j] = __builtin_amdgcn_mfma_f32_16x16x32_bf16(af[i], bfr[j], acc[i][j], 0, 0, 0);
    }
    __syncthreads();
  }

  // fused head: per column s, sum relu(z+pb)*fw over this block's 128 channels
  int quad = lane >> 4, nn = lane & 15;
  for (int j = 0; j < 4; j++) {
    float s = 0.f;
    for (int i = 0; i < 4; i++) {
      int c = cm + wm + i * 16 + quad * 4;
      f32x4 pbv = *reinterpret_cast<const f32x4*>(pb + c);
      f32x4 fwv = *reinterpret_cast<const f32x4*>(fw + c);
      for (int r = 0; r < 4; r++) {
        float z = acc[i][j][r] + pbv[r];
        z = fmaxf(z, 0.f);
        s += z * fwv[r];
      }
    }
    s += __shfl_xor(s, 16, 64);
    s += __shfl_xor(s, 32, 64);
    if (quad == 0) {
      int sc = s_base + wn + j * 16 + nn;
      if (3 * sc + KW <= slen) atomicAdd(partial + cum_q[b] + sc, s);
    }
  }
}

// ---- final: sigmoid(partial + fb) ----------------------------------------
__global__ void finalize(const float* __restrict__ partial, const float* __restrict__ fb,
                         float* __restrict__ out, int n) {
  int i = blockIdx.x * 256 + threadIdx.x;
  if (i < n) {
    float t = partial[i] + fb[0];
    out[i] = 1.f / (1.f + expf(-t));
  }
}

extern "C" void kernel_launch(void* const* d_in, const int* in_sizes, int n_in,
                              void* d_out, int out_size, void* d_ws, size_t ws_size,
                              hipStream_t stream) {
  (void)in_sizes; (void)n_in;
  const float* x   = (const float*)d_in[0];
  const float* w0  = (const float*)d_in[1];
  const float* b0  = (const float*)d_in[2];
  const float* g0  = (const float*)d_in[3];
  const float* be0 = (const float*)d_in[4];
  const float* w1  = (const float*)d_in[5];
  const float* b1  = (const float*)d_in[6];
  const float* g1  = (const float*)d_in[7];
  const float* be1 = (const float*)d_in[8];
  const float* w2  = (const float*)d_in[9];
  const float* b2  = (const float*)d_in[10];
  const float* g2  = (const float*)d_in[11];
  const float* be2 = (const float*)d_in[12];
  const float* pw  = (const float*)d_in[13];
  const float* pb  = (const float*)d_in[14];
  const float* fw  = (const float*)d_in[15];
  const float* fb  = (const float*)d_in[16];
  const int* seq_lens = (const int*)d_in[17];

  char* ws = (char*)d_ws;
  unsigned short* zeropage = (unsigned short*)ws;          // 4096 B, zeroed
  float* partial = (float*)(ws + 4096);                    // out_size floats, zeroed
  size_t off = 4096 + (size_t)out_size * 4;
  off = (off + 255) & ~(size_t)255;
  int* cum = (int*)(ws + off);                             // NB ints
  off += NB * 4;
  off = (off + 255) & ~(size_t)255;
  unsigned short* wt = (unsigned short*)(ws + off);        // 3 x 512 x 1536 bf16
  off += (size_t)3 * HCH * KDIM * 2;
  off = (off + 255) & ~(size_t)255;
  size_t fixed = off;

  // pick largest power-of-two batches-per-pass whose 2 ping-pong buffers fit
  const size_t per_batch = (size_t)LSEQ * HCH * 2;         // 4 MiB
  int nb_pass = NB;
  while (nb_pass > 1 && fixed + 2 * per_batch * (size_t)nb_pass > ws_size)
    nb_pass >>= 1;
  unsigned short* h0 = (unsigned short*)(ws + fixed);
  unsigned short* h1 = h0 + (size_t)nb_pass * LSEQ * HCH;

  int nzero = 1024 + out_size;   // zeropage (1024 floats) + partial
  prep_all<<<(3 * HCH * KDIM) / 256, 256, 0, stream>>>(w1, w2, pw, wt, seq_lens, cum,
                                                       (float*)ws, nzero);

  int npass = NB / nb_pass;
  for (int q = 0; q < npass; q++) {
    const float* xq = x + (size_t)q * nb_pass * LSEQ;
    const int* sq = seq_lens + q * nb_pass;
    layer0<<<nb_pass * (LSEQ / 32), 256, 0, stream>>>(xq, w0, b0, g0, be0, h0, sq);
    conv_gemm<<<dim3(4, nb_pass * 16), 256, 0, stream>>>(h0, wt, b1, g1, be1, h1,
                                                         zeropage, sq, 1);
    conv_gemm<<<dim3(4, nb_pass * 16), 256, 0, stream>>>(h1, wt + (size_t)HCH * KDIM,
                                                         b2, g2, be2, h0, zeropage, sq, 0);
    chunk_gemm<<<dim3(4, nb_pass * (SPAD / 128)), 256, 0, stream>>>(
        h0, wt + (size_t)2 * HCH * KDIM, pb, fw,
        sq, cum + q * nb_pass, partial, zeropage);
  }
  finalize<<<(out_size + 255) / 256, 256, 0, stream>>>(partial, fb, (float*)d_out, out_size);
}